// Round 8
// baseline (544.513 us; speedup 1.0000x reference)
//
#include <hip/hip_runtime.h>
#include <type_traits>

#define EMB_D 64
#define NCLS 8      // row-range partitions for degree kernel (XCD heuristic)
#define CSHIFT 11   // class = row >> 11 (2048 rows/class)
#define CMASK  ((1 << CSHIFT) - 1)
#define MAXC 128    // max classes (M <= 262144, also the 18-bit col limit)

typedef float    float4v __attribute__((ext_vector_type(4)));
typedef _Float16 half4v  __attribute__((ext_vector_type(4)));

__device__ inline float4v tof32(half4v v)  { return __builtin_convertvector(v, float4v); }
__device__ inline float4v tof32(float4v v) { return v; }

// ---------------------------------------------------------------------------
// fused partitioned degree kernel: bip degrees (deg, both dirs) + s-row
// degrees (degs). Class c only touches dst rows in its 1/8 of [0,M).
// ---------------------------------------------------------------------------
__global__ void deg_part_kernel(const int* __restrict__ eu, const int* __restrict__ ei,
                                int E, int U,
                                const int* __restrict__ sr, int S, int M,
                                int* __restrict__ deg, int* __restrict__ degs) {
    int cls = blockIdx.x & (NCLS - 1);
    long e  = ((long)(blockIdx.x >> 3)) * blockDim.x + threadIdx.x;
    int lo = (int)((long)cls * M / NCLS), hi = (int)((long)(cls + 1) * M / NCLS);
    if (e < E) {
        int u  = eu[e];
        int iv = U + ei[e];
        if (u  >= lo && u  < hi) atomicAdd(&deg[u], 1);
        if (iv >= lo && iv < hi) atomicAdd(&deg[iv], 1);
    }
    if (e < S) {
        int r = sr[e];
        int dst = U + r;
        if (dst >= lo && dst < hi) atomicAdd(&degs[r], 1);
    }
}

// ---------------------------------------------------------------------------
// scan phase 1 over combined row lengths; also emits norm = rsqrt(deg+1).
// ---------------------------------------------------------------------------
__global__ void __launch_bounds__(1024) scan_block(const int* __restrict__ deg,
                                                   const int* __restrict__ degs,
                                                   int U, int n,
                                                   float* __restrict__ norm,
                                                   int* __restrict__ incl,
                                                   int* __restrict__ bsum) {
    __shared__ int sh[1024];
    int i = blockIdx.x * 1024 + threadIdx.x;
    int d = (i < n) ? deg[i] : 0;
    int v = d;
    if (i < n && i >= U) v += degs[i - U];
    if (i < n) norm[i] = rsqrtf((float)d + 1.0f);
    sh[threadIdx.x] = v;
    __syncthreads();
    for (int ofs = 1; ofs < 1024; ofs <<= 1) {
        int t = (threadIdx.x >= ofs) ? sh[threadIdx.x - ofs] : 0;
        __syncthreads();
        sh[threadIdx.x] += t;
        __syncthreads();
    }
    if (i < n) incl[i] = sh[threadIdx.x];
    if (threadIdx.x == 1023) bsum[blockIdx.x] = sh[1023];
}

__global__ void __launch_bounds__(256) scan_bsum(int* __restrict__ bsum, int nb) {
    __shared__ int sh[256];
    int v = (threadIdx.x < nb) ? bsum[threadIdx.x] : 0;
    sh[threadIdx.x] = v;
    __syncthreads();
    for (int ofs = 1; ofs < 256; ofs <<= 1) {
        int t = (threadIdx.x >= ofs) ? sh[threadIdx.x - ofs] : 0;
        __syncthreads();
        sh[threadIdx.x] += t;
        __syncthreads();
    }
    if (threadIdx.x < nb) bsum[threadIdx.x] = sh[threadIdx.x] - v;  // exclusive
}

// rowptr + per-class bucket cursors (bucket regions == CSR class ranges)
__global__ void finalize_rowptr(const int* __restrict__ incl, const int* __restrict__ deg,
                                const int* __restrict__ degs,
                                const int* __restrict__ bsum, int U, int n,
                                int* __restrict__ rowptr, int* __restrict__ bkcur) {
    int i = blockIdx.x * blockDim.x + threadIdx.x;
    if (i < n) {
        int len = deg[i] + (i >= U ? degs[i - U] : 0);
        int v = incl[i] - len + bsum[i >> 10];
        rowptr[i] = v;
        if ((i & CMASK) == 0) bkcur[i >> CSHIFT] = v;
    } else if (i == n) {
        rowptr[n] = incl[n - 1] + bsum[(n - 1) >> 10];
    }
}

// ---------------------------------------------------------------------------
// pass 1: bin all entries into per-class buckets. LDS histogram ->
// one global atomicAdd per (block, class) -> contiguous per-block chunks
// (temporally dense appends: ~1x write amplification).
// Bucket entry: (row_lo<<18 | col, w_bits)  -- 8 B.
// ---------------------------------------------------------------------------
__global__ void __launch_bounds__(256) bin_kernel(const int* __restrict__ eu,
                                                  const int* __restrict__ ei,
                                                  int E, int nbE,
                                                  const int* __restrict__ sr,
                                                  const int* __restrict__ sc,
                                                  const float* __restrict__ sv, int S,
                                                  int U, const float* __restrict__ norm,
                                                  int* __restrict__ bkcur,
                                                  int2* __restrict__ bent) {
    __shared__ int hist[MAXC];
    __shared__ int base[MAXC];
    for (int t = threadIdx.x; t < MAXC; t += 256) hist[t] = 0;
    __syncthreads();

    int blk = blockIdx.x;
    int c0 = -1, c1 = -1;
    int2 e0 = make_int2(0, 0), e1 = make_int2(0, 0);
    if (blk < nbE) {
        int e = blk * 256 + threadIdx.x;
        if (e < E) {
            int u  = eu[e];
            int iv = U + ei[e];
            int wb = __float_as_int(norm[u] * norm[iv]);
            c0 = u >> CSHIFT;
            e0 = make_int2(((u & CMASK) << 18) | iv, wb);
            c1 = iv >> CSHIFT;
            e1 = make_int2(((iv & CMASK) << 18) | u, wb);
            atomicAdd(&hist[c0], 1);
            atomicAdd(&hist[c1], 1);
        }
    } else {
        int e = (blk - nbE) * 256 + threadIdx.x;
        if (e < S) {
            int dst = U + sr[e];
            c0 = dst >> CSHIFT;
            e0 = make_int2(((dst & CMASK) << 18) | (U + sc[e]), __float_as_int(sv[e]));
            atomicAdd(&hist[c0], 1);
        }
    }
    __syncthreads();
    for (int t = threadIdx.x; t < MAXC; t += 256) {
        int h = hist[t];
        base[t] = h ? atomicAdd(&bkcur[t], h) : 0;
        hist[t] = 0;
    }
    __syncthreads();
    if (c0 >= 0) {
        int o = atomicAdd(&hist[c0], 1);
        bent[base[c0] + o] = e0;
    }
    if (c1 >= 0) {
        int o = atomicAdd(&hist[c1], 1);
        bent[base[c1] + o] = e1;
    }
}

// ---------------------------------------------------------------------------
// pass 2: one 1024-thread block per class. Row cursors in LDS (8 KB, no
// global atomics). Reads its bucket sequentially, scatters into its ~280 KB
// CSR window (both L2-resident on one XCD -> ~1x write amplification).
// ---------------------------------------------------------------------------
__global__ void __launch_bounds__(1024) csr_scatter(const int* __restrict__ rowptr,
                                                    const int2* __restrict__ bent,
                                                    int2* __restrict__ ent, int M) {
    __shared__ int cur[1 << CSHIFT];
    int c  = blockIdx.x;
    int lo = c << CSHIFT;
    int hi = min(lo + (1 << CSHIFT), M);
    int nrows = hi - lo;
    for (int r = threadIdx.x; r < nrows; r += 1024)
        cur[r] = rowptr[lo + r];
    __syncthreads();
    int beg = rowptr[lo];
    int end = rowptr[hi];
    for (int k = beg + threadIdx.x; k < end; k += 1024) {
        int2 e = bent[k];
        int rl  = ((unsigned)e.x) >> 18;
        int col = e.x & 0x3FFFF;
        int p = atomicAdd(&cur[rl], 1);
        ent[p] = make_int2(col, e.y);
    }
}

// ---------------------------------------------------------------------------
// cur0 (fp16) = concat(user_emb, item_emb)
// ---------------------------------------------------------------------------
__global__ void init_kernel(const float4v* __restrict__ ue, const float4v* __restrict__ ie,
                            long u4, long total4, half4v* __restrict__ curH) {
    long stride = (long)gridDim.x * blockDim.x;
    for (long idx = (long)blockIdx.x * blockDim.x + threadIdx.x; idx < total4; idx += stride) {
        float4v v = (idx < u4) ? ue[idx] : ie[idx - u4];
        curH[idx] = __builtin_convertvector(v, half4v);
    }
}

// ---------------------------------------------------------------------------
// gather: ONE 16-lane quarter-wave per destination row (4 rows per wave),
// 4-deep masked software pipeline -> 16 outstanding row loads per wave.
// Heavy-first: item rows dispatched first, users fill the tail.
// MODE 0: read fp16 curH -> write fp16 dstH          (e0 -> e1)
// MODE 1: read fp16 curH -> dstF=e2 (fp32), out = e0+e1+e2
// MODE 2: read fp32 curF -> out = 0.25*(out + e3)
// ---------------------------------------------------------------------------
template <int MODE>
__global__ void __launch_bounds__(256) gather_kernel(const int* __restrict__ rowptr,
                                                     const int2* __restrict__ ent,
                                                     const _Float16* __restrict__ curH,
                                                     const float* __restrict__ curF,
                                                     const _Float16* __restrict__ cur0H,
                                                     _Float16* __restrict__ dstH,
                                                     float* __restrict__ dstF,
                                                     float* __restrict__ out,
                                                     int U, int I, int M) {
    using VecT = typename std::conditional<MODE == 2, float4v, half4v>::type;
    int raw = (int)((((long)blockIdx.x * blockDim.x) + threadIdx.x) >> 4);
    int l   = threadIdx.x & 15;
    if (raw >= M) return;
    int row = (raw < I) ? (U + raw) : (raw - I);
    int beg = rowptr[row];
    int end = rowptr[row + 1];
    const VecT* curv = (MODE == 2) ? (const VecT*)(const void*)curF
                                   : (const VecT*)(const void*)curH;

    float4v acc = {0.f, 0.f, 0.f, 0.f};
    int j = beg;
    int2 a0 = (j + 0 < end) ? ent[j + 0] : make_int2(0, 0);
    int2 a1 = (j + 1 < end) ? ent[j + 1] : make_int2(0, 0);
    int2 a2 = (j + 2 < end) ? ent[j + 2] : make_int2(0, 0);
    int2 a3 = (j + 3 < end) ? ent[j + 3] : make_int2(0, 0);
    VecT v0 = curv[(long)a0.x * 16 + l];
    VecT v1 = curv[(long)a1.x * 16 + l];
    VecT v2 = curv[(long)a2.x * 16 + l];
    VecT v3 = curv[(long)a3.x * 16 + l];
    while (j + 4 < end) {
        int jn = j + 4;
        int2 b0 = (jn + 0 < end) ? ent[jn + 0] : make_int2(0, 0);
        int2 b1 = (jn + 1 < end) ? ent[jn + 1] : make_int2(0, 0);
        int2 b2 = (jn + 2 < end) ? ent[jn + 2] : make_int2(0, 0);
        int2 b3 = (jn + 3 < end) ? ent[jn + 3] : make_int2(0, 0);
        VecT u0 = curv[(long)b0.x * 16 + l];
        VecT u1 = curv[(long)b1.x * 16 + l];
        VecT u2 = curv[(long)b2.x * 16 + l];
        VecT u3 = curv[(long)b3.x * 16 + l];
        acc += __int_as_float(a0.y) * tof32(v0);
        acc += __int_as_float(a1.y) * tof32(v1);
        acc += __int_as_float(a2.y) * tof32(v2);
        acc += __int_as_float(a3.y) * tof32(v3);
        a0 = b0; a1 = b1; a2 = b2; a3 = b3;
        v0 = u0; v1 = u1; v2 = u2; v3 = u3;
        j = jn;
    }
    acc += __int_as_float(a0.y) * tof32(v0);
    acc += __int_as_float(a1.y) * tof32(v1);
    acc += __int_as_float(a2.y) * tof32(v2);
    acc += __int_as_float(a3.y) * tof32(v3);

    long o4 = (long)row * 16 + l;
    if (MODE == 0) {
        ((half4v*)dstH)[o4] = __builtin_convertvector(acc, half4v);
    } else if (MODE == 1) {
        float4v e0 = tof32(((const half4v*)cur0H)[o4]);
        float4v e1 = tof32(((const half4v*)curH)[o4]);
        ((float4v*)dstF)[o4] = acc;              // e2 (fp32) for layer 3
        ((float4v*)out)[o4]  = e0 + e1 + acc;    // partial sum e0+e1+e2
    } else {
        float4v pv = ((const float4v*)out)[o4];
        ((float4v*)out)[o4] = 0.25f * (pv + acc);
    }
}

extern "C" void kernel_launch(void* const* d_in, const int* in_sizes, int n_in,
                              void* d_out, int out_size, void* d_ws, size_t ws_size,
                              hipStream_t stream) {
    const float* user_emb = (const float*)d_in[0];
    const float* item_emb = (const float*)d_in[1];
    const int*   edge_user = (const int*)d_in[2];
    const int*   edge_item = (const int*)d_in[3];
    const int*   s_row = (const int*)d_in[4];
    const int*   s_col = (const int*)d_in[5];
    const float* s_val = (const float*)d_in[6];
    float* out = (float*)d_out;

    const int U = in_sizes[0] / EMB_D;
    const int I = in_sizes[1] / EMB_D;
    const int M = U + I;
    const int E = in_sizes[2];
    const int S = in_sizes[4];
    const long MD = (long)M * EMB_D;
    const long NT = 2L * E + S;       // merged CSR entries
    const int NC = (M + CMASK) >> CSHIFT;   // number of row classes

    // workspace carve-up, 16B-aligned chunks
    char* p = (char*)d_ws;
    auto carve = [&](long bytes) {
        char* q = p;
        p += (bytes + 15) & ~15L;
        return q;
    };
    _Float16* cur0H  = (_Float16*)carve(MD * sizeof(_Float16));  // e0 (fp16)
    _Float16* cur1H  = (_Float16*)carve(MD * sizeof(_Float16));  // e1 (fp16)
    // bufC (e2, fp32) aliases the bucket array: bucket is dead before e2 is written
    long aliasBytes = MD * sizeof(float) > (NT + 8) * (long)sizeof(int2)
                        ? MD * sizeof(float) : (NT + 8) * (long)sizeof(int2);
    char* aliasRgn = carve(aliasBytes);
    float* bufC  = (float*)aliasRgn;
    int2*  bent  = (int2*)aliasRgn;
    float* norm    = (float*)carve((long)M * sizeof(float));
    int*   deg_all = (int*)carve((long)(M + I) * sizeof(int));   // deg | degs adjacent
    int*   deg     = deg_all;
    int*   degs    = deg_all + M;
    int*   incl    = (int*)carve((long)M * sizeof(int));
    int*   rowptr  = (int*)carve((long)(M + 1) * sizeof(int));
    int*   bsum    = (int*)carve(256 * sizeof(int));
    int*   bkcur   = (int*)carve(MAXC * sizeof(int));
    int2*  ent     = (int2*)carve((NT + 8) * sizeof(int2));

    const int nb1 = (M + 1023) / 1024;
    const int nbE = (E + 255) / 256;
    const int nbS = (S + 255) / 256;
    const int nbMax = (nbE > nbS) ? nbE : nbS;

    // 1) fused partitioned degrees
    hipMemsetAsync(deg_all, 0, (size_t)(M + I) * sizeof(int), stream);
    deg_part_kernel<<<NCLS * nbMax, 256, 0, stream>>>(edge_user, edge_item, E, U,
                                                      s_row, S, M, deg, degs);

    // 2) single scan over combined row lengths (also emits norm)
    scan_block<<<nb1, 1024, 0, stream>>>(deg, degs, U, M, norm, incl, bsum);
    scan_bsum<<<1, 256, 0, stream>>>(bsum, nb1);
    finalize_rowptr<<<(M + 256) / 256, 256, 0, stream>>>(incl, deg, degs, bsum, U, M,
                                                         rowptr, bkcur);

    // 3) two-pass CSR build: dense bucket append, then per-class LDS scatter
    bin_kernel<<<nbE + nbS, 256, 0, stream>>>(edge_user, edge_item, E, nbE,
                                              s_row, s_col, s_val, S,
                                              U, norm, bkcur, bent);
    csr_scatter<<<NC, 1024, 0, stream>>>(rowptr, bent, ent, M);

    // 4) init cur0 (fp16)
    init_kernel<<<2048, 256, 0, stream>>>((const float4v*)user_emb, (const float4v*)item_emb,
                                          (long)U * (EMB_D / 4), MD / 4, (half4v*)cur0H);

    // 5) L=3 gather layers: fp16 reads for layers 1-2, fp32 for layer 3
    const int gblocks = (int)(((long)M * 16 + 255) / 256);
    gather_kernel<0><<<gblocks, 256, 0, stream>>>(rowptr, ent, cur0H, nullptr, nullptr,
                                                  cur1H, nullptr, nullptr, U, I, M);
    gather_kernel<1><<<gblocks, 256, 0, stream>>>(rowptr, ent, cur1H, nullptr, cur0H,
                                                  nullptr, bufC, out, U, I, M);
    gather_kernel<2><<<gblocks, 256, 0, stream>>>(rowptr, ent, nullptr, bufC, nullptr,
                                                  nullptr, nullptr, out, U, I, M);
}

// Round 9
// 498.869 us; speedup vs baseline: 1.0915x; 1.0915x over previous
//
#include <hip/hip_runtime.h>
#include <type_traits>

#define EMB_D 64
#define NCLS 8      // row-range partitions for degree kernel (XCD heuristic)
#define CSHIFT 11   // class = row >> 11 (2048 rows/class)
#define CMASK  ((1 << CSHIFT) - 1)
#define MAXC 128    // max classes (M <= 262144, also the 18-bit col limit)
#define CPAD 16     // bkcur padding: one counter per 64B line

typedef float    float4v __attribute__((ext_vector_type(4)));
typedef _Float16 half4v  __attribute__((ext_vector_type(4)));

__device__ inline float4v tof32(half4v v)  { return __builtin_convertvector(v, float4v); }
__device__ inline float4v tof32(float4v v) { return v; }

// ---------------------------------------------------------------------------
// fused partitioned degree kernel: bip degrees (deg, both dirs) + s-row
// degrees (degs). Class c only touches dst rows in its 1/8 of [0,M).
// ---------------------------------------------------------------------------
__global__ void deg_part_kernel(const int* __restrict__ eu, const int* __restrict__ ei,
                                int E, int U,
                                const int* __restrict__ sr, int S, int M,
                                int* __restrict__ deg, int* __restrict__ degs) {
    int cls = blockIdx.x & (NCLS - 1);
    long e  = ((long)(blockIdx.x >> 3)) * blockDim.x + threadIdx.x;
    int lo = (int)((long)cls * M / NCLS), hi = (int)((long)(cls + 1) * M / NCLS);
    if (e < E) {
        int u  = eu[e];
        int iv = U + ei[e];
        if (u  >= lo && u  < hi) atomicAdd(&deg[u], 1);
        if (iv >= lo && iv < hi) atomicAdd(&deg[iv], 1);
    }
    if (e < S) {
        int r = sr[e];
        int dst = U + r;
        if (dst >= lo && dst < hi) atomicAdd(&degs[r], 1);
    }
}

// ---------------------------------------------------------------------------
// scan phase 1 over combined row lengths; also emits norm = rsqrt(deg+1).
// ---------------------------------------------------------------------------
__global__ void __launch_bounds__(1024) scan_block(const int* __restrict__ deg,
                                                   const int* __restrict__ degs,
                                                   int U, int n,
                                                   float* __restrict__ norm,
                                                   int* __restrict__ incl,
                                                   int* __restrict__ bsum) {
    __shared__ int sh[1024];
    int i = blockIdx.x * 1024 + threadIdx.x;
    int d = (i < n) ? deg[i] : 0;
    int v = d;
    if (i < n && i >= U) v += degs[i - U];
    if (i < n) norm[i] = rsqrtf((float)d + 1.0f);
    sh[threadIdx.x] = v;
    __syncthreads();
    for (int ofs = 1; ofs < 1024; ofs <<= 1) {
        int t = (threadIdx.x >= ofs) ? sh[threadIdx.x - ofs] : 0;
        __syncthreads();
        sh[threadIdx.x] += t;
        __syncthreads();
    }
    if (i < n) incl[i] = sh[threadIdx.x];
    if (threadIdx.x == 1023) bsum[blockIdx.x] = sh[1023];
}

__global__ void __launch_bounds__(256) scan_bsum(int* __restrict__ bsum, int nb) {
    __shared__ int sh[256];
    int v = (threadIdx.x < nb) ? bsum[threadIdx.x] : 0;
    sh[threadIdx.x] = v;
    __syncthreads();
    for (int ofs = 1; ofs < 256; ofs <<= 1) {
        int t = (threadIdx.x >= ofs) ? sh[threadIdx.x - ofs] : 0;
        __syncthreads();
        sh[threadIdx.x] += t;
        __syncthreads();
    }
    if (threadIdx.x < nb) bsum[threadIdx.x] = sh[threadIdx.x] - v;  // exclusive
}

// rowptr + per-row cursor + per-class bucket cursors (padded) + class table
__global__ void finalize_rowptr(const int* __restrict__ incl, const int* __restrict__ deg,
                                const int* __restrict__ degs,
                                const int* __restrict__ bsum, int U, int n, int NC,
                                int* __restrict__ rowptr, int* __restrict__ cursor,
                                int* __restrict__ bkcur, int* __restrict__ bkptr) {
    int i = blockIdx.x * blockDim.x + threadIdx.x;
    if (i < n) {
        int len = deg[i] + (i >= U ? degs[i - U] : 0);
        int v = incl[i] - len + bsum[i >> 10];
        rowptr[i] = v;
        cursor[i] = v;
        if ((i & CMASK) == 0) {
            bkcur[(i >> CSHIFT) * CPAD] = v;   // one counter per 64B line
            bkptr[i >> CSHIFT] = v;
        }
    } else if (i == n) {
        int tot = incl[n - 1] + bsum[(n - 1) >> 10];
        rowptr[n] = tot;
        bkptr[NC] = tot;
    }
}

// ---------------------------------------------------------------------------
// pass 1: bin entries into per-class buckets. 512 edges per block (2/thread,
// statically unrolled). LDS histogram -> ONE padded global atomicAdd per
// (block, class) -> contiguous per-block chunks (dense writes, low
// atomic-line contention).  Bucket entry: (row_lo<<18 | col, w_bits).
// ---------------------------------------------------------------------------
__global__ void __launch_bounds__(256) bin_kernel(const int* __restrict__ eu,
                                                  const int* __restrict__ ei,
                                                  int E, int nbE,
                                                  const int* __restrict__ sr,
                                                  const int* __restrict__ sc,
                                                  const float* __restrict__ sv, int S,
                                                  int U, const float* __restrict__ norm,
                                                  int* __restrict__ bkcur,
                                                  int2* __restrict__ bent) {
    __shared__ int hist[MAXC];
    __shared__ int base[MAXC];
    if (threadIdx.x < MAXC) hist[threadIdx.x] = 0;
    __syncthreads();

    int blk = blockIdx.x;
    int c0 = -1, c1 = -1, c2 = -1, c3 = -1;
    int2 v0, v1, v2, v3;
    if (blk < nbE) {
        {
            int e = blk * 512 + threadIdx.x;
            if (e < E) {
                int u  = eu[e];
                int iv = U + ei[e];
                int wb = __float_as_int(norm[u] * norm[iv]);
                c0 = u >> CSHIFT;  v0 = make_int2(((u & CMASK) << 18) | iv, wb);
                c1 = iv >> CSHIFT; v1 = make_int2(((iv & CMASK) << 18) | u, wb);
                atomicAdd(&hist[c0], 1);
                atomicAdd(&hist[c1], 1);
            }
        }
        {
            int e = blk * 512 + 256 + threadIdx.x;
            if (e < E) {
                int u  = eu[e];
                int iv = U + ei[e];
                int wb = __float_as_int(norm[u] * norm[iv]);
                c2 = u >> CSHIFT;  v2 = make_int2(((u & CMASK) << 18) | iv, wb);
                c3 = iv >> CSHIFT; v3 = make_int2(((iv & CMASK) << 18) | u, wb);
                atomicAdd(&hist[c2], 1);
                atomicAdd(&hist[c3], 1);
            }
        }
    } else {
        {
            int e = (blk - nbE) * 512 + threadIdx.x;
            if (e < S) {
                int dst = U + sr[e];
                c0 = dst >> CSHIFT;
                v0 = make_int2(((dst & CMASK) << 18) | (U + sc[e]), __float_as_int(sv[e]));
                atomicAdd(&hist[c0], 1);
            }
        }
        {
            int e = (blk - nbE) * 512 + 256 + threadIdx.x;
            if (e < S) {
                int dst = U + sr[e];
                c1 = dst >> CSHIFT;
                v1 = make_int2(((dst & CMASK) << 18) | (U + sc[e]), __float_as_int(sv[e]));
                atomicAdd(&hist[c1], 1);
            }
        }
    }
    __syncthreads();
    if (threadIdx.x < MAXC) {
        int h = hist[threadIdx.x];
        base[threadIdx.x] = h ? atomicAdd(&bkcur[threadIdx.x * CPAD], h) : 0;
        hist[threadIdx.x] = 0;
    }
    __syncthreads();
    if (c0 >= 0) { int o = atomicAdd(&hist[c0], 1); bent[base[c0] + o] = v0; }
    if (c1 >= 0) { int o = atomicAdd(&hist[c1], 1); bent[base[c1] + o] = v1; }
    if (c2 >= 0) { int o = atomicAdd(&hist[c2], 1); bent[base[c2] + o] = v2; }
    if (c3 >= 0) { int o = atomicAdd(&hist[c3], 1); bent[base[c3] + o] = v3; }
}

// ---------------------------------------------------------------------------
// pass 2: entry-parallel CSR scatter. Class recovered by binary search in the
// LDS-cached class-boundary table; per-row cursor via global atomic (150K
// spread words -- cheap). Bucket order == class order, so concurrent blocks
// write into a ~1 MB moving window of ent -> lines fill while L2-resident.
// ---------------------------------------------------------------------------
__global__ void __launch_bounds__(256) csr_scatter(const int* __restrict__ bkptr, int NC,
                                                   const int2* __restrict__ bent,
                                                   int* __restrict__ cursor,
                                                   int2* __restrict__ ent, int NT) {
    __shared__ int bp[MAXC + 1];
    for (int t = threadIdx.x; t <= NC; t += 256) bp[t] = bkptr[t];
    __syncthreads();
    int k = blockIdx.x * 256 + threadIdx.x;
    if (k >= NT) return;
    int2 e = bent[k];
    // largest c with bp[c] <= k
    int lo = 0, hi = NC - 1;
    while (lo < hi) {
        int mid = (lo + hi + 1) >> 1;
        if (bp[mid] <= k) lo = mid; else hi = mid - 1;
    }
    int row = (lo << CSHIFT) | (((unsigned)e.x) >> 18);
    int col = e.x & 0x3FFFF;
    int p = atomicAdd(&cursor[row], 1);
    ent[p] = make_int2(col, e.y);
}

// ---------------------------------------------------------------------------
// cur0 (fp16) = concat(user_emb, item_emb)
// ---------------------------------------------------------------------------
__global__ void init_kernel(const float4v* __restrict__ ue, const float4v* __restrict__ ie,
                            long u4, long total4, half4v* __restrict__ curH) {
    long stride = (long)gridDim.x * blockDim.x;
    for (long idx = (long)blockIdx.x * blockDim.x + threadIdx.x; idx < total4; idx += stride) {
        float4v v = (idx < u4) ? ue[idx] : ie[idx - u4];
        curH[idx] = __builtin_convertvector(v, half4v);
    }
}

// ---------------------------------------------------------------------------
// gather: ONE 16-lane quarter-wave per destination row (4 rows per wave),
// 4-deep masked software pipeline -> 16 outstanding row loads per wave.
// Heavy-first: item rows dispatched first, users fill the tail.
// MODE 0: read fp16 curH -> write fp16 dstH          (e0 -> e1)
// MODE 1: read fp16 curH -> dstF=e2 (fp32), out = e0+e1+e2
// MODE 2: read fp32 curF -> out = 0.25*(out + e3)
// ---------------------------------------------------------------------------
template <int MODE>
__global__ void __launch_bounds__(256) gather_kernel(const int* __restrict__ rowptr,
                                                     const int2* __restrict__ ent,
                                                     const _Float16* __restrict__ curH,
                                                     const float* __restrict__ curF,
                                                     const _Float16* __restrict__ cur0H,
                                                     _Float16* __restrict__ dstH,
                                                     float* __restrict__ dstF,
                                                     float* __restrict__ out,
                                                     int U, int I, int M) {
    using VecT = typename std::conditional<MODE == 2, float4v, half4v>::type;
    int raw = (int)((((long)blockIdx.x * blockDim.x) + threadIdx.x) >> 4);
    int l   = threadIdx.x & 15;
    if (raw >= M) return;
    int row = (raw < I) ? (U + raw) : (raw - I);
    int beg = rowptr[row];
    int end = rowptr[row + 1];
    const VecT* curv = (MODE == 2) ? (const VecT*)(const void*)curF
                                   : (const VecT*)(const void*)curH;

    float4v acc = {0.f, 0.f, 0.f, 0.f};
    int j = beg;
    int2 a0 = (j + 0 < end) ? ent[j + 0] : make_int2(0, 0);
    int2 a1 = (j + 1 < end) ? ent[j + 1] : make_int2(0, 0);
    int2 a2 = (j + 2 < end) ? ent[j + 2] : make_int2(0, 0);
    int2 a3 = (j + 3 < end) ? ent[j + 3] : make_int2(0, 0);
    VecT v0 = curv[(long)a0.x * 16 + l];
    VecT v1 = curv[(long)a1.x * 16 + l];
    VecT v2 = curv[(long)a2.x * 16 + l];
    VecT v3 = curv[(long)a3.x * 16 + l];
    while (j + 4 < end) {
        int jn = j + 4;
        int2 b0 = (jn + 0 < end) ? ent[jn + 0] : make_int2(0, 0);
        int2 b1 = (jn + 1 < end) ? ent[jn + 1] : make_int2(0, 0);
        int2 b2 = (jn + 2 < end) ? ent[jn + 2] : make_int2(0, 0);
        int2 b3 = (jn + 3 < end) ? ent[jn + 3] : make_int2(0, 0);
        VecT u0 = curv[(long)b0.x * 16 + l];
        VecT u1 = curv[(long)b1.x * 16 + l];
        VecT u2 = curv[(long)b2.x * 16 + l];
        VecT u3 = curv[(long)b3.x * 16 + l];
        acc += __int_as_float(a0.y) * tof32(v0);
        acc += __int_as_float(a1.y) * tof32(v1);
        acc += __int_as_float(a2.y) * tof32(v2);
        acc += __int_as_float(a3.y) * tof32(v3);
        a0 = b0; a1 = b1; a2 = b2; a3 = b3;
        v0 = u0; v1 = u1; v2 = u2; v3 = u3;
        j = jn;
    }
    acc += __int_as_float(a0.y) * tof32(v0);
    acc += __int_as_float(a1.y) * tof32(v1);
    acc += __int_as_float(a2.y) * tof32(v2);
    acc += __int_as_float(a3.y) * tof32(v3);

    long o4 = (long)row * 16 + l;
    if (MODE == 0) {
        ((half4v*)dstH)[o4] = __builtin_convertvector(acc, half4v);
    } else if (MODE == 1) {
        float4v e0 = tof32(((const half4v*)cur0H)[o4]);
        float4v e1 = tof32(((const half4v*)curH)[o4]);
        ((float4v*)dstF)[o4] = acc;              // e2 (fp32) for layer 3
        ((float4v*)out)[o4]  = e0 + e1 + acc;    // partial sum e0+e1+e2
    } else {
        float4v pv = ((const float4v*)out)[o4];
        ((float4v*)out)[o4] = 0.25f * (pv + acc);
    }
}

extern "C" void kernel_launch(void* const* d_in, const int* in_sizes, int n_in,
                              void* d_out, int out_size, void* d_ws, size_t ws_size,
                              hipStream_t stream) {
    const float* user_emb = (const float*)d_in[0];
    const float* item_emb = (const float*)d_in[1];
    const int*   edge_user = (const int*)d_in[2];
    const int*   edge_item = (const int*)d_in[3];
    const int*   s_row = (const int*)d_in[4];
    const int*   s_col = (const int*)d_in[5];
    const float* s_val = (const float*)d_in[6];
    float* out = (float*)d_out;

    const int U = in_sizes[0] / EMB_D;
    const int I = in_sizes[1] / EMB_D;
    const int M = U + I;
    const int E = in_sizes[2];
    const int S = in_sizes[4];
    const long MD = (long)M * EMB_D;
    const long NT = 2L * E + S;             // merged CSR entries
    const int NC = (M + CMASK) >> CSHIFT;   // number of row classes

    // workspace carve-up, 16B-aligned chunks
    char* p = (char*)d_ws;
    auto carve = [&](long bytes) {
        char* q = p;
        p += (bytes + 15) & ~15L;
        return q;
    };
    _Float16* cur0H  = (_Float16*)carve(MD * sizeof(_Float16));  // e0 (fp16)
    _Float16* cur1H  = (_Float16*)carve(MD * sizeof(_Float16));  // e1 (fp16)
    // bufC (e2, fp32) aliases the bucket array: bucket dead before e2 written
    long aliasBytes = MD * sizeof(float) > (NT + 8) * (long)sizeof(int2)
                        ? MD * sizeof(float) : (NT + 8) * (long)sizeof(int2);
    char* aliasRgn = carve(aliasBytes);
    float* bufC  = (float*)aliasRgn;
    int2*  bent  = (int2*)aliasRgn;
    float* norm    = (float*)carve((long)M * sizeof(float));
    int*   deg_all = (int*)carve((long)(M + I) * sizeof(int));   // deg | degs adjacent
    int*   deg     = deg_all;
    int*   degs    = deg_all + M;
    int*   incl    = (int*)carve((long)M * sizeof(int));
    int*   rowptr  = (int*)carve((long)(M + 1) * sizeof(int));
    int*   cursor  = (int*)carve((long)M * sizeof(int));
    int*   bsum    = (int*)carve(256 * sizeof(int));
    int*   bkcur   = (int*)carve((long)MAXC * CPAD * sizeof(int));
    int*   bkptr   = (int*)carve((long)(MAXC + 1) * sizeof(int));
    int2*  ent     = (int2*)carve((NT + 8) * sizeof(int2));

    const int nb1 = (M + 1023) / 1024;
    const int nbE = (E + 255) / 256;
    const int nbS = (S + 255) / 256;
    const int nbMax = (nbE > nbS) ? nbE : nbS;
    const int nbE2 = (E + 511) / 512;       // bin blocks (512 edges each)
    const int nbS2 = (S + 511) / 512;

    // 1) fused partitioned degrees
    hipMemsetAsync(deg_all, 0, (size_t)(M + I) * sizeof(int), stream);
    deg_part_kernel<<<NCLS * nbMax, 256, 0, stream>>>(edge_user, edge_item, E, U,
                                                      s_row, S, M, deg, degs);

    // 2) single scan over combined row lengths (also emits norm)
    scan_block<<<nb1, 1024, 0, stream>>>(deg, degs, U, M, norm, incl, bsum);
    scan_bsum<<<1, 256, 0, stream>>>(bsum, nb1);
    finalize_rowptr<<<(M + 256) / 256, 256, 0, stream>>>(incl, deg, degs, bsum, U, M, NC,
                                                         rowptr, cursor, bkcur, bkptr);

    // 3) two-pass CSR build: dense bucket append, then entry-parallel scatter
    bin_kernel<<<nbE2 + nbS2, 256, 0, stream>>>(edge_user, edge_item, E, nbE2,
                                                s_row, s_col, s_val, S,
                                                U, norm, bkcur, bent);
    csr_scatter<<<(int)((NT + 255) / 256), 256, 0, stream>>>(bkptr, NC, bent, cursor,
                                                             ent, (int)NT);

    // 4) init cur0 (fp16)
    init_kernel<<<2048, 256, 0, stream>>>((const float4v*)user_emb, (const float4v*)item_emb,
                                          (long)U * (EMB_D / 4), MD / 4, (half4v*)cur0H);

    // 5) L=3 gather layers: fp16 reads for layers 1-2, fp32 for layer 3
    const int gblocks = (int)(((long)M * 16 + 255) / 256);
    gather_kernel<0><<<gblocks, 256, 0, stream>>>(rowptr, ent, cur0H, nullptr, nullptr,
                                                  cur1H, nullptr, nullptr, U, I, M);
    gather_kernel<1><<<gblocks, 256, 0, stream>>>(rowptr, ent, cur1H, nullptr, cur0H,
                                                  nullptr, bufC, out, U, I, M);
    gather_kernel<2><<<gblocks, 256, 0, stream>>>(rowptr, ent, nullptr, bufC, nullptr,
                                                  nullptr, nullptr, out, U, I, M);
}